// Round 14
// baseline (260.477 us; speedup 1.0000x reference)
//
#include <hip/hip_runtime.h>
#include <math.h>

#define DD 128          // node embedding dim
#define RR 1024         // root nodes
#define TT 4            // trunk types; encoder TT is the output autoencoder
#define LL 64           // levels
#define MM 2048         // nodes per level
#define NBK 16          // nodes per chunk (one MFMA M-tile)
#define GT 39           // chunk slots per trunk type (cap 624; mean 486+pad<=45 -> 4.8σ)
#define GO 13           // chunk slots for output type (cap 208; mean 102+pad<=45 -> 6.2σ)
#define CCAP (4*GT + GO)       // 169 global chunk slots per level == #WGs
#define PAD16 (CCAP*NBK)       // 2704 order slots per level
#define CH CCAP
#define NFLAGS (LL*CCAP*8)     // per (level, chunk, wave) flags

typedef __attribute__((ext_vector_type(8))) short short8v;   // 8 bf16 (4 VGPRs)
typedef __attribute__((ext_vector_type(4))) float f32x4;

static __device__ __forceinline__ unsigned short f2bf(float f) {
    unsigned u = __float_as_uint(f);
    unsigned r = (u + 0x7fffu + ((u >> 16) & 1u)) >> 16;   // RNE
    return (unsigned short)r;
}

// A&S 7.1.26 erf (|err| < 1.5e-7), branchless
static __device__ __forceinline__ float gelu_f(float h) {
    float x  = h * 0.70710678118654752f;
    float ax = fabsf(x);
    float t  = __builtin_amdgcn_rcpf(fmaf(0.3275911f, ax, 1.0f));
    float p  = fmaf(t, 1.061405429f, -1.453152027f);
    p = fmaf(p, t, 1.421413741f);
    p = fmaf(p, t, -0.284496736f);
    p = fmaf(p, t, 0.254829592f);
    p = p * t;
    float er = 1.0f - p * __expf(-ax * ax);
    er = copysignf(er, x);
    return 0.5f * h * (1.0f + er);
}

// is node-index p (global, may be root) a "gate" node (has a parent from its
// immediately preceding level)? Computable from par[]/types[] alone.
static __device__ __forceinline__ bool parent_is_gate(
    int p, const int* __restrict__ par, const int* __restrict__ types) {
    if (p < RR) return false;
    int pidx = p - RR;
    int pl = pidx >> 11;            // parent's level
    if (pl == 0) return false;      // level-0 parents are roots only
    int pthr = RR + (pl - 1)*MM;
    int pp0 = par[2*pidx];
    bool g = (pp0 >= pthr);
    if (types[pidx] < TT) {
        int pp1 = par[2*pidx + 1];
        g = g || (pp1 >= pthr);
    }
    return g;
}

// ---------------------------------------------------------------------------
// Fused prep. 3-way bucketing per type region:
//   sail  (no level-(l-1) parent)                  -> waits nothing recent
//   gate1 (recent parents exist, all are sail)     -> waits only early pubs
//   gate2 (>=1 recent parent is itself gate)       -> the true chain links
// Regions fixed per type (static weights); chunkof[node] = global chunk id.
// ---------------------------------------------------------------------------
__global__ __launch_bounds__(256) void prep_all(
    const float* __restrict__ root, const float* __restrict__ W1,
    const float* __restrict__ W2, const int* __restrict__ types,
    const int* __restrict__ par,
    float* __restrict__ buf,
    unsigned short* __restrict__ W1F, unsigned short* __restrict__ W2F,
    unsigned short* __restrict__ order, unsigned char* __restrict__ chunkof,
    unsigned int* __restrict__ flags)
{
    int bid = blockIdx.x, tid = threadIdx.x;
    if (bid < LL) {
        int l = bid;
        __shared__ int cnt[15], cur[15];
        if (tid < 15) cnt[tid] = 0;
        __syncthreads();
        for (int s = tid; s < PAD16; s += 256) order[l*PAD16 + s] = 0xFFFFu;
        int thr = RR + (l-1)*MM;    // parents >= thr come from level l-1
        for (int m = tid; m < MM; m += 256) {
            int gi = l*MM + m;
            int t = types[gi];
            int e = (t >= TT) ? TT : t;
            int p0 = par[2*gi];
            bool r0 = (p0 >= RR) && (p0 >= thr);
            bool g0 = r0 && parent_is_gate(p0, par, types);
            bool rec = r0, gat = g0;
            if (t < TT) {
                int p1 = par[2*gi + 1];
                bool r1 = (p1 >= RR) && (p1 >= thr);
                rec = rec || r1;
                gat = gat || (r1 && parent_is_gate(p1, par, types));
            }
            int b = rec ? (gat ? 2 : 1) : 0;
            atomicAdd(&cnt[e*3 + b], 1);
        }
        __syncthreads();
        if (tid == 0) {
            for (int e = 0; e < 5; e++) {
                int base = ((e < 4) ? e*GT : 4*GT) * NBK;
                int s0 = ((cnt[e*3]     + NBK - 1)/NBK)*NBK;
                int s1 = ((cnt[e*3 + 1] + NBK - 1)/NBK)*NBK;
                cur[e*3]     = base;
                cur[e*3 + 1] = base + s0;
                cur[e*3 + 2] = base + s0 + s1;
            }
        }
        __syncthreads();
        for (int m = tid; m < MM; m += 256) {
            int gi = l*MM + m;
            int t = types[gi];
            int e = (t >= TT) ? TT : t;
            int p0 = par[2*gi];
            bool r0 = (p0 >= RR) && (p0 >= thr);
            bool g0 = r0 && parent_is_gate(p0, par, types);
            bool rec = r0, gat = g0;
            if (t < TT) {
                int p1 = par[2*gi + 1];
                bool r1 = (p1 >= RR) && (p1 >= thr);
                rec = rec || r1;
                gat = gat || (r1 && parent_is_gate(p1, par, types));
            }
            int b = rec ? (gat ? 2 : 1) : 0;
            int pos = atomicAdd(&cur[e*3 + b], 1);
            order[l*PAD16 + pos] = (unsigned short)m;
            chunkof[l*MM + m] = (unsigned char)(pos >> 4);   // global chunk id
        }
    } else if (bid < LL + 240) {
        int t0 = (bid - LL)*256 + tid;
        if (t0 < 5*16*8*64) {
            int lane = t0 & 63;
            int kk = (t0 >> 6) & 7;
            int nt = (t0 >> 9) & 15;
            int e  = t0 >> 13;
            int n  = nt*16 + (lane & 15);
            int k0 = kk*32 + (lane >> 4)*8;
            unsigned short v[8];
            #pragma unroll
            for (int j = 0; j < 8; j++) v[j] = f2bf(W1[(e*256 + k0 + j)*256 + n]);
            *(short8v*)&W1F[t0*8] = *(short8v*)v;
        } else {
            int t = t0 - 5*16*8*64;   // < 20480
            int lane = t & 63;
            int kk = (t >> 6) & 7;
            int nt = (t >> 9) & 7;
            int e  = t >> 12;
            int n  = nt*16 + (lane & 15);
            int k0 = kk*32 + (lane >> 4)*8;
            unsigned short v[8];
            #pragma unroll
            for (int j = 0; j < 8; j++) v[j] = f2bf(W2[(e*256 + k0 + j)*128 + n]);
            *(short8v*)&W2F[t*8] = *(short8v*)v;
        }
    } else if (bid < LL + 240 + 32) {
        int idx = (bid - (LL + 240))*256 + tid;   // 0..8191
        const f32x4* r4 = (const f32x4*)root;
        f32x4* o4 = (f32x4*)buf;
        #pragma unroll
        for (int q = 0; q < 4; q++) o4[idx*4 + q] = r4[idx*4 + q];
    } else {
        // zero per-wave flags (guarded)
        int idx = (bid - (LL + 240 + 32))*256 + tid;
        #pragma unroll
        for (int q = 0; q < 8; q++) {
            int fi = idx*8 + q;
            if (fi < NFLAGS) flags[fi] = 0u;
        }
    }
}

// ---------------------------------------------------------------------------
// Persistent dataflow kernel: CCAP WGs x 512 threads (8 waves). Static encoder
// type per WG; weights in VGPRs (r12). Per-wave flags (r13): producer wave w
// drains its own sc1 stores and publishes its own flag. Consumer thread
// (m, seg) depends on exactly one producer wave -> per-thread flag index.
// Snapshot carried 1 level, fresh re-load hidden under L1 MFMA, phase-B spin
// only for genuine same-level parents. 3-way sail/gate1/gate2 bucketing.
// ---------------------------------------------------------------------------
__global__ __launch_bounds__(512, 2) void persist_mfma(
    const unsigned short* __restrict__ W1F, const unsigned short* __restrict__ W2F,
    const float* __restrict__ b1, const float* __restrict__ b2,
    const float* __restrict__ slots, const int* __restrict__ par,
    const int* __restrict__ types, const unsigned short* __restrict__ order,
    const unsigned char* __restrict__ chunkof,
    float* __restrict__ buf, unsigned int* __restrict__ flags)
{
    __shared__ int4 descs[LL][NBK];            // {node, p0, p1(~slot if out), etype}
    __shared__ int2 descs2[LL][NBK];           // producer chunk id per parent (-1 ready)
    __shared__ int ech[LL];
    __shared__ unsigned short axFA[8*64*8];    // A-frags of x, 8 KB
    __shared__ unsigned short axFB[8*64*8];    // double buffer, 8 KB
    __shared__ unsigned short hxF[8*64*8];     // A-frags of h, 8 KB

    int tid = threadIdx.x;
    int wg  = blockIdx.x;
    int e_wg = (wg < 4*GT) ? (wg / GT) : TT;   // static encoder type of this WG

    int w  = tid >> 6;    // wave 0..7
    int lq = tid & 63;    // lane
    int m_own   = tid >> 4;   // gather row (tid<256)
    int seg_own = tid & 15;   // 16-float segment

    // ---- preload weight B-fragments + biases into registers ----
    short8v w1r0[8], w1r1[8], w2r[8];
    #pragma unroll
    for (int kk = 0; kk < 8; kk++) {
        w1r0[kk] = *(const short8v*)&W1F[(((e_wg*16 + 2*w + 0)*8 + kk)*64 + lq)*8];
        w1r1[kk] = *(const short8v*)&W1F[(((e_wg*16 + 2*w + 1)*8 + kk)*64 + lq)*8];
        w2r[kk]  = *(const short8v*)&W2F[(((e_wg*8  + w)*8 + kk)*64 + lq)*8];
    }
    float b1v0 = b1[e_wg*256 + (2*w + 0)*16 + (lq & 15)];
    float b1v1 = b1[e_wg*256 + (2*w + 1)*16 + (lq & 15)];
    float b2v  = b2[e_wg*128 + w*16 + (lq & 15)];

    // ---- prologue: resolve all levels' descriptors + producer chunk ids ----
    for (int i = tid; i < LL*NBK; i += 512) {
        int l = i >> 4, s = i & 15;
        unsigned short o = order[l*PAD16 + wg*NBK + s];
        int4 d; int2 d2 = make_int2(-1, -1);
        if (o == 0xFFFFu) {
            d = make_int4(-1, 0, 0, -1);
        } else {
            int gi = l*MM + (int)o;
            int t = types[gi];
            int e = (t >= TT) ? TT : t;
            int p0 = par[2*gi];
            int p1 = (t >= TT) ? ~(t - TT) : par[2*gi + 1];
            d = make_int4((int)o, p0, p1, e);
            if (p0 >= RR) d2.x = ((p0 - RR) >> 11)*CCAP + (int)chunkof[p0 - RR];
            if (p1 >= RR) d2.y = ((p1 - RR) >> 11)*CCAP + (int)chunkof[p1 - RR];
        }
        descs[l][s] = d;
        descs2[l][s] = d2;
    }
    __syncthreads();
    for (int i = tid; i < LL; i += 512) ech[i] = descs[i][0].w;
    __syncthreads();

    // resolve this thread's gather source + per-wave flag index for level l1
    #define RESOLVE(l1, S, F8, P) {                                            \
        int4 d_ = descs[l1][m_own];                                            \
        if (d_.x < 0) { P = true; S = nullptr; F8 = -1; }                      \
        else {                                                                 \
            P = false;                                                         \
            int2 d2_ = descs2[l1][m_own];                                      \
            if (seg_own < 8)  { S = buf + (size_t)d_.y*DD + seg_own*16;        \
                                F8 = (d2_.x >= 0) ? d2_.x*8 + seg_own : -1; }  \
            else if (d_.z < 0){ S = slots + (size_t)(~d_.z)*DD + (seg_own-8)*16; F8 = -1; } \
            else              { S = buf + (size_t)d_.z*DD + (seg_own-8)*16;    \
                                F8 = (d2_.y >= 0) ? d2_.y*8 + (seg_own-8) : -1; } \
        } }

    #define WRITE_FRAGS(AXT, V0, V1, V2, V3) {                                 \
        unsigned short tA_[8], tB_[8];                                         \
        _Pragma("unroll")                                                      \
        for (int j = 0; j < 4; j++) {                                          \
            tA_[j]   = f2bf(V0[j]); tA_[4+j] = f2bf(V1[j]);                    \
            tB_[j]   = f2bf(V2[j]); tB_[4+j] = f2bf(V3[j]);                    \
        }                                                                      \
        int k_ = seg_own*16;                                                   \
        int kk_ = k_ >> 5, ln_ = m_own + 16*((k_ >> 3) & 3);                   \
        *(short8v*)&AXT[(kk_*64 + ln_)*8] = *(short8v*)tA_;                    \
        k_ += 8; kk_ = k_ >> 5; ln_ = m_own + 16*((k_ >> 3) & 3);              \
        *(short8v*)&AXT[(kk_*64 + ln_)*8] = *(short8v*)tB_;                    \
    }

    // ---- level-0 gather (roots/slots: always ready) ----
    if (tid < 256) {
        const float* src; int f8; bool pad;
        RESOLVE(0, src, f8, pad);
        f32x4 z = (f32x4){0.f,0.f,0.f,0.f};
        f32x4 v0 = z, v1 = z, v2 = z, v3 = z;
        if (!pad) {
            const f32x4* s4 = (const f32x4*)src;
            v0 = s4[0]; v1 = s4[1]; v2 = s4[2]; v3 = s4[3];
        }
        WRITE_FRAGS(axFA, v0, v1, v2, v3);
    }
    // per-thread gather carry + flag snapshot for level 1
    const float* srcC = nullptr; int fiC = -1; bool padC = true; unsigned fvC = 1u;
    if (tid < 256) {
        RESOLVE(1, srcC, fiC, padC);
        if (!padC && fiC >= 0)
            fvC = __hip_atomic_load(&flags[fiC], __ATOMIC_RELAXED, __HIP_MEMORY_SCOPE_AGENT);
    }
    __syncthreads();

    unsigned short* axc = axFA;
    unsigned short* axn = axFB;

    for (int l = 0; l < LL; l++) {
        bool havN = (l + 1 < LL);

        // ---- phase A: row loads for snapshot-confirmed-ready parents ----
        bool pend = false; unsigned fv2 = 0u;
        f32x4 z = (f32x4){0.f,0.f,0.f,0.f};
        f32x4 v0 = z, v1 = z, v2 = z, v3 = z;
        if (havN && tid < 256 && !padC) {
            bool ready = (fiC < 0) || (fvC != 0u);
            if (ready) {
                asm volatile("" ::: "memory");
                const f32x4* s4 = (const f32x4*)srcC;
                v0 = s4[0]; v1 = s4[1]; v2 = s4[2]; v3 = s4[3];
            } else {
                pend = true;
                fv2 = __hip_atomic_load(&flags[fiC], __ATOMIC_RELAXED,
                                        __HIP_MEMORY_SCOPE_AGENT);
            }
        }
        __builtin_amdgcn_sched_barrier(0);   // pin: loads issued before compute

        int e = ech[l];
        if (e >= 0) {
            // ---- layer 1: H = GELU(X @ W1 + b1), weights in VGPRs ----
            f32x4 acc0 = (f32x4){b1v0, b1v0, b1v0, b1v0};
            f32x4 acc1 = (f32x4){b1v1, b1v1, b1v1, b1v1};
            {
                const short8v* Ab = (const short8v*)axc;
                #pragma unroll
                for (int kk = 0; kk < 8; kk++) {
                    short8v a = Ab[kk*64 + lq];
                    acc0 = __builtin_amdgcn_mfma_f32_16x16x32_bf16(a, w1r0[kk], acc0, 0, 0, 0);
                    acc1 = __builtin_amdgcn_mfma_f32_16x16x32_bf16(a, w1r1[kk], acc1, 0, 0, 0);
                }
            }
            // ---- mid-check: late flag arrived? issue row loads now (hidden) ----
            if (pend && fv2 != 0u) {
                asm volatile("" ::: "memory");
                const f32x4* s4 = (const f32x4*)srcC;
                v0 = s4[0]; v1 = s4[1]; v2 = s4[2]; v3 = s4[3];
                pend = false;
            }
            __builtin_amdgcn_sched_barrier(0);

            // GELU + scatter H into A-frag LDS (nt = 2w+c, c in {0,1})
            #pragma unroll
            for (int c = 0; c < 2; c++) {
                int nh = (2*w + c)*16 + (lq & 15);
                int kk2 = nh >> 5;
                int jj  = nh & 7;
                int lhi = 16*((nh >> 3) & 3);
                #pragma unroll
                for (int r = 0; r < 4; r++) {
                    int m = (lq >> 4)*4 + r;
                    float h = (c == 0) ? acc0[r] : acc1[r];
                    hxF[(kk2*64 + (m + lhi))*8 + jj] = f2bf(gelu_f(h));
                }
            }
            __syncthreads();

            // ---- layer 2: OUT = H @ W2 + b2 (nt = w) ----
            f32x4 acc2 = (f32x4){b2v, b2v, b2v, b2v};
            {
                const short8v* Hb = (const short8v*)hxF;
                #pragma unroll
                for (int kk = 0; kk < 8; kk++) {
                    short8v a = Hb[kk*64 + lq];
                    acc2 = __builtin_amdgcn_mfma_f32_16x16x32_bf16(a, w2r[kk], acc2, 0, 0, 0);
                }
            }
            // result rows: sc1 write-through to the coherence point
            int baserow = RR + l*MM;
            int n = w*16 + (lq & 15);
            #pragma unroll
            for (int r = 0; r < 4; r++) {
                int m = (lq >> 4)*4 + r;
                int node = descs[l][m].x;
                if (node >= 0)
                    __hip_atomic_store(&buf[(size_t)(baserow + node)*DD + n], acc2[r],
                                       __ATOMIC_RELAXED, __HIP_MEMORY_SCOPE_AGENT);
            }
            // per-wave drain (vmcnt is per-wave) -> publish THIS WAVE's flag
            asm volatile("s_waitcnt vmcnt(0)" ::: "memory");
            if ((tid & 63) == 0)
                __hip_atomic_store(&flags[(l*CCAP + wg)*8 + w], 1u, __ATOMIC_RELAXED,
                                   __HIP_MEMORY_SCOPE_AGENT);
        }

        // ---- snapshot issue for level l+2 (per-thread; consumed at bottom) ----
        const float* srcN = nullptr; int fiN = -1; bool padN = true; unsigned fvN = 1u;
        if (l + 2 < LL && tid < 256) {
            RESOLVE(l+2, srcN, fiN, padN);
            if (!padN && fiN >= 0)
                fvN = __hip_atomic_load(&flags[fiN], __ATOMIC_RELAXED,
                                        __HIP_MEMORY_SCOPE_AGENT);
        }

        // ---- phase B: spin only on genuine same-level (gate) parents ----
        if (havN && tid < 256) {
            if (pend) {
                while (__hip_atomic_load(&flags[fiC], __ATOMIC_RELAXED,
                                         __HIP_MEMORY_SCOPE_AGENT) == 0u)
                    __builtin_amdgcn_s_sleep(1);
                asm volatile("" ::: "memory");
                const f32x4* s4 = (const f32x4*)srcC;
                v0 = s4[0]; v1 = s4[1]; v2 = s4[2]; v3 = s4[3];
            }
            WRITE_FRAGS(axn, v0, v1, v2, v3);
        }

        __syncthreads();
        unsigned short* t2 = axc; axc = axn; axn = t2;
        srcC = srcN; fiC = fiN; padC = padN; fvC = fvN;
    }
}

extern "C" void kernel_launch(void* const* d_in, const int* in_sizes, int n_in,
                              void* d_out, int out_size, void* d_ws, size_t ws_size,
                              hipStream_t stream) {
    const float* root  = (const float*)d_in[0];   // (1024, 128)
    const float* W1    = (const float*)d_in[1];   // (5, 256, 256)
    const float* b1    = (const float*)d_in[2];   // (5, 256)
    const float* W2    = (const float*)d_in[3];   // (5, 256, 128)
    const float* b2    = (const float*)d_in[4];   // (5, 128)
    const float* slots = (const float*)d_in[5];   // (256, 128)
    const int*   par   = (const int*)d_in[6];     // (131072, 2)
    const int*   typ   = (const int*)d_in[7];     // (131072,)
    float* out = (float*)d_out;                   // (132096, 128)

    unsigned short* W1F     = (unsigned short*)d_ws;          // 327680 shorts
    unsigned short* W2F     = W1F + 5*16*8*64*8;              // 163840 shorts
    unsigned short* order   = W2F + 5*8*8*64*8;               // 64*2704 shorts
    unsigned char*  chunkof = (unsigned char*)(order + LL*PAD16);  // 131072 B
    unsigned int*   flags   = (unsigned int*)(chunkof + LL*MM);    // NFLAGS u32

    // single fused prep dispatch (order/chunkof, weights, roots, flags)
    prep_all<<<LL + 240 + 32 + 48, 256, 0, stream>>>(root, W1, W2, typ, par, out,
                                                     W1F, W2F, order, chunkof, flags);

    // persistent dataflow sweep (co-residency guaranteed by cooperative launch)
    void* args[] = { (void*)&W1F, (void*)&W2F, (void*)&b1, (void*)&b2,
                     (void*)&slots, (void*)&par, (void*)&typ, (void*)&order,
                     (void*)&chunkof, (void*)&out, (void*)&flags };
    hipLaunchCooperativeKernel((const void*)persist_mfma, dim3(CH), dim3(512),
                               args, 0, stream);
}

// Round 15
// 257.631 us; speedup vs baseline: 1.0110x; 1.0110x over previous
//
#include <hip/hip_runtime.h>
#include <math.h>

#define DD 128          // node embedding dim
#define RR 1024         // root nodes
#define TT 4            // trunk types; encoder TT is the output autoencoder
#define LL 64           // levels
#define MM 2048         // nodes per level
#define NBK 16          // nodes per chunk (one MFMA M-tile)
#define GT 37           // chunk slots per trunk type (cap 592 nodes, mean 486, 5.4σ)
#define GO 10           // chunk slots for output type (cap 160, mean 102, 5.8σ)
#define CCAP (4*GT + GO)       // 158 global chunk slots per level == #WGs
#define PAD16 (CCAP*NBK)       // 2528 order slots per level
#define CH CCAP
#define NFLAGS (LL*CCAP*8)     // per (level, chunk, wave) flags

typedef __attribute__((ext_vector_type(8))) short short8v;   // 8 bf16 (4 VGPRs)
typedef __attribute__((ext_vector_type(4))) float f32x4;

static __device__ __forceinline__ unsigned short f2bf(float f) {
    unsigned u = __float_as_uint(f);
    unsigned r = (u + 0x7fffu + ((u >> 16) & 1u)) >> 16;   // RNE
    return (unsigned short)r;
}

// A&S 7.1.26 erf (|err| < 1.5e-7), branchless
static __device__ __forceinline__ float gelu_f(float h) {
    float x  = h * 0.70710678118654752f;
    float ax = fabsf(x);
    float t  = __builtin_amdgcn_rcpf(fmaf(0.3275911f, ax, 1.0f));
    float p  = fmaf(t, 1.061405429f, -1.453152027f);
    p = fmaf(p, t, 1.421413741f);
    p = fmaf(p, t, -0.284496736f);
    p = fmaf(p, t, 0.254829592f);
    p = p * t;
    float er = 1.0f - p * __expf(-ax * ax);
    er = copysignf(er, x);
    return 0.5f * h * (1.0f + er);
}

// ---------------------------------------------------------------------------
// Fused prep. 2-way sail/gate bucketing per type region (r11/r13), PLUS a
// per-level ROTATION of chunk slots within each type region so gate duty
// round-robins across WGs instead of pinning to the same top slots at every
// level. chunkof[node] = global chunk id (rotated).
// ---------------------------------------------------------------------------
__global__ __launch_bounds__(256) void prep_all(
    const float* __restrict__ root, const float* __restrict__ W1,
    const float* __restrict__ W2, const int* __restrict__ types,
    const int* __restrict__ par,
    float* __restrict__ buf,
    unsigned short* __restrict__ W1F, unsigned short* __restrict__ W2F,
    unsigned short* __restrict__ order, unsigned char* __restrict__ chunkof,
    unsigned int* __restrict__ flags)
{
    int bid = blockIdx.x, tid = threadIdx.x;
    if (bid < LL) {
        int l = bid;
        __shared__ int cnt[10], cur[10];
        if (tid < 10) cnt[tid] = 0;
        __syncthreads();
        for (int s = tid; s < PAD16; s += 256) order[l*PAD16 + s] = 0xFFFFu;
        int thr = RR + (l-1)*MM;    // parents >= thr come from level l-1
        for (int m = tid; m < MM; m += 256) {
            int gi = l*MM + m;
            int t = types[gi];
            int e = (t >= TT) ? TT : t;
            int p0 = par[2*gi];
            bool rec = (p0 >= RR) && (p0 >= thr);
            if (t < TT) {
                int p1 = par[2*gi + 1];
                rec = rec || ((p1 >= RR) && (p1 >= thr));
            }
            atomicAdd(&cnt[e*2 + (rec ? 1 : 0)], 1);
        }
        __syncthreads();
        if (tid == 0) {
            for (int e = 0; e < 5; e++) {
                cur[e*2]     = 0;                              // local linear, sail
                cur[e*2 + 1] = ((cnt[e*2] + NBK - 1)/NBK)*NBK; // gate after sail pad
            }
        }
        __syncthreads();
        for (int m = tid; m < MM; m += 256) {
            int gi = l*MM + m;
            int t = types[gi];
            int e = (t >= TT) ? TT : t;
            int p0 = par[2*gi];
            bool rec = (p0 >= RR) && (p0 >= thr);
            if (t < TT) {
                int p1 = par[2*gi + 1];
                rec = rec || ((p1 >= RR) && (p1 >= thr));
            }
            int lin = atomicAdd(&cur[e*2 + (rec ? 1 : 0)], 1);  // local in region
            int G     = (e < 4) ? GT : GO;
            int rbase = (e < 4) ? e*GT : 4*GT;
            int rot   = (e < 4) ? (l*13) % GT : (l*3) % GO;     // coprime strides
            int cl    = (lin >> 4) + rot;
            if (cl >= G) cl -= G;
            int c = rbase + cl;                                 // rotated chunk id
            order[l*PAD16 + c*NBK + (lin & 15)] = (unsigned short)m;
            chunkof[l*MM + m] = (unsigned char)c;
        }
    } else if (bid < LL + 240) {
        int t0 = (bid - LL)*256 + tid;
        if (t0 < 5*16*8*64) {
            int lane = t0 & 63;
            int kk = (t0 >> 6) & 7;
            int nt = (t0 >> 9) & 15;
            int e  = t0 >> 13;
            int n  = nt*16 + (lane & 15);
            int k0 = kk*32 + (lane >> 4)*8;
            unsigned short v[8];
            #pragma unroll
            for (int j = 0; j < 8; j++) v[j] = f2bf(W1[(e*256 + k0 + j)*256 + n]);
            *(short8v*)&W1F[t0*8] = *(short8v*)v;
        } else {
            int t = t0 - 5*16*8*64;   // < 20480
            int lane = t & 63;
            int kk = (t >> 6) & 7;
            int nt = (t >> 9) & 7;
            int e  = t >> 12;
            int n  = nt*16 + (lane & 15);
            int k0 = kk*32 + (lane >> 4)*8;
            unsigned short v[8];
            #pragma unroll
            for (int j = 0; j < 8; j++) v[j] = f2bf(W2[(e*256 + k0 + j)*128 + n]);
            *(short8v*)&W2F[t*8] = *(short8v*)v;
        }
    } else if (bid < LL + 240 + 32) {
        int idx = (bid - (LL + 240))*256 + tid;   // 0..8191
        const f32x4* r4 = (const f32x4*)root;
        f32x4* o4 = (f32x4*)buf;
        #pragma unroll
        for (int q = 0; q < 4; q++) o4[idx*4 + q] = r4[idx*4 + q];
    } else {
        // zero per-wave flags (guarded)
        int idx = (bid - (LL + 240 + 32))*256 + tid;
        #pragma unroll
        for (int q = 0; q < 8; q++) {
            int fi = idx*8 + q;
            if (fi < NFLAGS) flags[fi] = 0u;
        }
    }
}

// ---------------------------------------------------------------------------
// Persistent dataflow kernel (r13 verbatim): CCAP WGs x 512 threads (8 waves).
// Static encoder type per WG; weights in VGPRs. Per-wave flags: producer wave
// w drains its own sc1 stores and publishes its own flag. Consumer thread
// (m, seg) depends on exactly one producer wave -> per-thread flag index.
// Snapshot carried 1 level, fresh re-load hidden under L1 MFMA, phase-B spin
// only for genuine same-level (gate) parents.
// ---------------------------------------------------------------------------
__global__ __launch_bounds__(512, 2) void persist_mfma(
    const unsigned short* __restrict__ W1F, const unsigned short* __restrict__ W2F,
    const float* __restrict__ b1, const float* __restrict__ b2,
    const float* __restrict__ slots, const int* __restrict__ par,
    const int* __restrict__ types, const unsigned short* __restrict__ order,
    const unsigned char* __restrict__ chunkof,
    float* __restrict__ buf, unsigned int* __restrict__ flags)
{
    __shared__ int4 descs[LL][NBK];            // {node, p0, p1(~slot if out), etype}
    __shared__ int2 descs2[LL][NBK];           // producer chunk id per parent (-1 ready)
    __shared__ int ech[LL];
    __shared__ unsigned short axFA[8*64*8];    // A-frags of x, 8 KB
    __shared__ unsigned short axFB[8*64*8];    // double buffer, 8 KB
    __shared__ unsigned short hxF[8*64*8];     // A-frags of h, 8 KB

    int tid = threadIdx.x;
    int wg  = blockIdx.x;
    int e_wg = (wg < 4*GT) ? (wg / GT) : TT;   // static encoder type of this WG

    int w  = tid >> 6;    // wave 0..7
    int lq = tid & 63;    // lane
    int m_own   = tid >> 4;   // gather row (tid<256)
    int seg_own = tid & 15;   // 16-float segment

    // ---- preload weight B-fragments + biases into registers ----
    short8v w1r0[8], w1r1[8], w2r[8];
    #pragma unroll
    for (int kk = 0; kk < 8; kk++) {
        w1r0[kk] = *(const short8v*)&W1F[(((e_wg*16 + 2*w + 0)*8 + kk)*64 + lq)*8];
        w1r1[kk] = *(const short8v*)&W1F[(((e_wg*16 + 2*w + 1)*8 + kk)*64 + lq)*8];
        w2r[kk]  = *(const short8v*)&W2F[(((e_wg*8  + w)*8 + kk)*64 + lq)*8];
    }
    float b1v0 = b1[e_wg*256 + (2*w + 0)*16 + (lq & 15)];
    float b1v1 = b1[e_wg*256 + (2*w + 1)*16 + (lq & 15)];
    float b2v  = b2[e_wg*128 + w*16 + (lq & 15)];

    // ---- prologue: resolve all levels' descriptors + producer chunk ids ----
    for (int i = tid; i < LL*NBK; i += 512) {
        int l = i >> 4, s = i & 15;
        unsigned short o = order[l*PAD16 + wg*NBK + s];
        int4 d; int2 d2 = make_int2(-1, -1);
        if (o == 0xFFFFu) {
            d = make_int4(-1, 0, 0, -1);
        } else {
            int gi = l*MM + (int)o;
            int t = types[gi];
            int e = (t >= TT) ? TT : t;
            int p0 = par[2*gi];
            int p1 = (t >= TT) ? ~(t - TT) : par[2*gi + 1];
            d = make_int4((int)o, p0, p1, e);
            if (p0 >= RR) d2.x = ((p0 - RR) >> 11)*CCAP + (int)chunkof[p0 - RR];
            if (p1 >= RR) d2.y = ((p1 - RR) >> 11)*CCAP + (int)chunkof[p1 - RR];
        }
        descs[l][s] = d;
        descs2[l][s] = d2;
    }
    __syncthreads();
    for (int i = tid; i < LL; i += 512) ech[i] = descs[i][0].w;
    __syncthreads();

    // resolve this thread's gather source + per-wave flag index for level l1
    #define RESOLVE(l1, S, F8, P) {                                            \
        int4 d_ = descs[l1][m_own];                                            \
        if (d_.x < 0) { P = true; S = nullptr; F8 = -1; }                      \
        else {                                                                 \
            P = false;                                                         \
            int2 d2_ = descs2[l1][m_own];                                      \
            if (seg_own < 8)  { S = buf + (size_t)d_.y*DD + seg_own*16;        \
                                F8 = (d2_.x >= 0) ? d2_.x*8 + seg_own : -1; }  \
            else if (d_.z < 0){ S = slots + (size_t)(~d_.z)*DD + (seg_own-8)*16; F8 = -1; } \
            else              { S = buf + (size_t)d_.z*DD + (seg_own-8)*16;    \
                                F8 = (d2_.y >= 0) ? d2_.y*8 + (seg_own-8) : -1; } \
        } }

    #define WRITE_FRAGS(AXT, V0, V1, V2, V3) {                                 \
        unsigned short tA_[8], tB_[8];                                         \
        _Pragma("unroll")                                                      \
        for (int j = 0; j < 4; j++) {                                          \
            tA_[j]   = f2bf(V0[j]); tA_[4+j] = f2bf(V1[j]);                    \
            tB_[j]   = f2bf(V2[j]); tB_[4+j] = f2bf(V3[j]);                    \
        }                                                                      \
        int k_ = seg_own*16;                                                   \
        int kk_ = k_ >> 5, ln_ = m_own + 16*((k_ >> 3) & 3);                   \
        *(short8v*)&AXT[(kk_*64 + ln_)*8] = *(short8v*)tA_;                    \
        k_ += 8; kk_ = k_ >> 5; ln_ = m_own + 16*((k_ >> 3) & 3);              \
        *(short8v*)&AXT[(kk_*64 + ln_)*8] = *(short8v*)tB_;                    \
    }

    // ---- level-0 gather (roots/slots: always ready) ----
    if (tid < 256) {
        const float* src; int f8; bool pad;
        RESOLVE(0, src, f8, pad);
        f32x4 z = (f32x4){0.f,0.f,0.f,0.f};
        f32x4 v0 = z, v1 = z, v2 = z, v3 = z;
        if (!pad) {
            const f32x4* s4 = (const f32x4*)src;
            v0 = s4[0]; v1 = s4[1]; v2 = s4[2]; v3 = s4[3];
        }
        WRITE_FRAGS(axFA, v0, v1, v2, v3);
    }
    // per-thread gather carry + flag snapshot for level 1
    const float* srcC = nullptr; int fiC = -1; bool padC = true; unsigned fvC = 1u;
    if (tid < 256) {
        RESOLVE(1, srcC, fiC, padC);
        if (!padC && fiC >= 0)
            fvC = __hip_atomic_load(&flags[fiC], __ATOMIC_RELAXED, __HIP_MEMORY_SCOPE_AGENT);
    }
    __syncthreads();

    unsigned short* axc = axFA;
    unsigned short* axn = axFB;

    for (int l = 0; l < LL; l++) {
        bool havN = (l + 1 < LL);

        // ---- phase A: row loads for snapshot-confirmed-ready parents ----
        bool pend = false; unsigned fv2 = 0u;
        f32x4 z = (f32x4){0.f,0.f,0.f,0.f};
        f32x4 v0 = z, v1 = z, v2 = z, v3 = z;
        if (havN && tid < 256 && !padC) {
            bool ready = (fiC < 0) || (fvC != 0u);
            if (ready) {
                asm volatile("" ::: "memory");
                const f32x4* s4 = (const f32x4*)srcC;
                v0 = s4[0]; v1 = s4[1]; v2 = s4[2]; v3 = s4[3];
            } else {
                pend = true;
                fv2 = __hip_atomic_load(&flags[fiC], __ATOMIC_RELAXED,
                                        __HIP_MEMORY_SCOPE_AGENT);
            }
        }
        __builtin_amdgcn_sched_barrier(0);   // pin: loads issued before compute

        int e = ech[l];
        if (e >= 0) {
            // ---- layer 1: H = GELU(X @ W1 + b1), weights in VGPRs ----
            f32x4 acc0 = (f32x4){b1v0, b1v0, b1v0, b1v0};
            f32x4 acc1 = (f32x4){b1v1, b1v1, b1v1, b1v1};
            {
                const short8v* Ab = (const short8v*)axc;
                #pragma unroll
                for (int kk = 0; kk < 8; kk++) {
                    short8v a = Ab[kk*64 + lq];
                    acc0 = __builtin_amdgcn_mfma_f32_16x16x32_bf16(a, w1r0[kk], acc0, 0, 0, 0);
                    acc1 = __builtin_amdgcn_mfma_f32_16x16x32_bf16(a, w1r1[kk], acc1, 0, 0, 0);
                }
            }
            // ---- mid-check: late flag arrived? issue row loads now (hidden) ----
            if (pend && fv2 != 0u) {
                asm volatile("" ::: "memory");
                const f32x4* s4 = (const f32x4*)srcC;
                v0 = s4[0]; v1 = s4[1]; v2 = s4[2]; v3 = s4[3];
                pend = false;
            }
            __builtin_amdgcn_sched_barrier(0);

            // GELU + scatter H into A-frag LDS (nt = 2w+c, c in {0,1})
            #pragma unroll
            for (int c = 0; c < 2; c++) {
                int nh = (2*w + c)*16 + (lq & 15);
                int kk2 = nh >> 5;
                int jj  = nh & 7;
                int lhi = 16*((nh >> 3) & 3);
                #pragma unroll
                for (int r = 0; r < 4; r++) {
                    int m = (lq >> 4)*4 + r;
                    float h = (c == 0) ? acc0[r] : acc1[r];
                    hxF[(kk2*64 + (m + lhi))*8 + jj] = f2bf(gelu_f(h));
                }
            }
            __syncthreads();

            // ---- layer 2: OUT = H @ W2 + b2 (nt = w) ----
            f32x4 acc2 = (f32x4){b2v, b2v, b2v, b2v};
            {
                const short8v* Hb = (const short8v*)hxF;
                #pragma unroll
                for (int kk = 0; kk < 8; kk++) {
                    short8v a = Hb[kk*64 + lq];
                    acc2 = __builtin_amdgcn_mfma_f32_16x16x32_bf16(a, w2r[kk], acc2, 0, 0, 0);
                }
            }
            // result rows: sc1 write-through to the coherence point
            int baserow = RR + l*MM;
            int n = w*16 + (lq & 15);
            #pragma unroll
            for (int r = 0; r < 4; r++) {
                int m = (lq >> 4)*4 + r;
                int node = descs[l][m].x;
                if (node >= 0)
                    __hip_atomic_store(&buf[(size_t)(baserow + node)*DD + n], acc2[r],
                                       __ATOMIC_RELAXED, __HIP_MEMORY_SCOPE_AGENT);
            }
            // per-wave drain (vmcnt is per-wave) -> publish THIS WAVE's flag
            asm volatile("s_waitcnt vmcnt(0)" ::: "memory");
            if ((tid & 63) == 0)
                __hip_atomic_store(&flags[(l*CCAP + wg)*8 + w], 1u, __ATOMIC_RELAXED,
                                   __HIP_MEMORY_SCOPE_AGENT);
        }

        // ---- snapshot issue for level l+2 (per-thread; consumed at bottom) ----
        const float* srcN = nullptr; int fiN = -1; bool padN = true; unsigned fvN = 1u;
        if (l + 2 < LL && tid < 256) {
            RESOLVE(l+2, srcN, fiN, padN);
            if (!padN && fiN >= 0)
                fvN = __hip_atomic_load(&flags[fiN], __ATOMIC_RELAXED,
                                        __HIP_MEMORY_SCOPE_AGENT);
        }

        // ---- phase B: spin only on genuine same-level (gate) parents ----
        if (havN && tid < 256) {
            if (pend) {
                while (__hip_atomic_load(&flags[fiC], __ATOMIC_RELAXED,
                                         __HIP_MEMORY_SCOPE_AGENT) == 0u)
                    __builtin_amdgcn_s_sleep(1);
                asm volatile("" ::: "memory");
                const f32x4* s4 = (const f32x4*)srcC;
                v0 = s4[0]; v1 = s4[1]; v2 = s4[2]; v3 = s4[3];
            }
            WRITE_FRAGS(axn, v0, v1, v2, v3);
        }

        __syncthreads();
        unsigned short* t2 = axc; axc = axn; axn = t2;
        srcC = srcN; fiC = fiN; padC = padN; fvC = fvN;
    }
}

extern "C" void kernel_launch(void* const* d_in, const int* in_sizes, int n_in,
                              void* d_out, int out_size, void* d_ws, size_t ws_size,
                              hipStream_t stream) {
    const float* root  = (const float*)d_in[0];   // (1024, 128)
    const float* W1    = (const float*)d_in[1];   // (5, 256, 256)
    const float* b1    = (const float*)d_in[2];   // (5, 256)
    const float* W2    = (const float*)d_in[3];   // (5, 256, 128)
    const float* b2    = (const float*)d_in[4];   // (5, 128)
    const float* slots = (const float*)d_in[5];   // (256, 128)
    const int*   par   = (const int*)d_in[6];     // (131072, 2)
    const int*   typ   = (const int*)d_in[7];     // (131072,)
    float* out = (float*)d_out;                   // (132096, 128)

    unsigned short* W1F     = (unsigned short*)d_ws;          // 327680 shorts
    unsigned short* W2F     = W1F + 5*16*8*64*8;              // 163840 shorts
    unsigned short* order   = W2F + 5*8*8*64*8;               // 64*2528 shorts
    unsigned char*  chunkof = (unsigned char*)(order + LL*PAD16);  // 131072 B
    unsigned int*   flags   = (unsigned int*)(chunkof + LL*MM);    // NFLAGS u32

    // single fused prep dispatch (order/chunkof, weights, roots, flags)
    prep_all<<<LL + 240 + 32 + 40, 256, 0, stream>>>(root, W1, W2, typ, par, out,
                                                     W1F, W2F, order, chunkof, flags);

    // persistent dataflow sweep (co-residency guaranteed by cooperative launch)
    void* args[] = { (void*)&W1F, (void*)&W2F, (void*)&b1, (void*)&b2,
                     (void*)&slots, (void*)&par, (void*)&typ, (void*)&order,
                     (void*)&chunkof, (void*)&out, (void*)&flags };
    hipLaunchCooperativeKernel((const void*)persist_mfma, dim3(CH), dim3(512),
                               args, 0, stream);
}